// Round 1
// baseline (544.025 us; speedup 1.0000x reference)
//
#include <hip/hip_runtime.h>

// Unfold (im2col) disguised as depthwise conv with eye(9) kernels.
// x: [16, 64, 112, 112] f32 -> out: [16, 64*9, 112, 112] f32
// out[n, c*9+j, h, w] = x[n, c, h + j/3 - 1, w + j%3 - 1] (zero pad)

#define NN 16
#define CC 64
#define HH 112
#define WW 112
#define KK 9
#define W4 (WW / 4)   // 28 float4 per row

__global__ __launch_bounds__(256) void unfold_kernel(const float* __restrict__ x,
                                                     float* __restrict__ out,
                                                     unsigned total4) {
    unsigned idx = blockIdx.x * 256u + threadIdx.x;
    if (idx >= total4) return;

    // Decode flat float4 index -> (n, cj, h, w4). Unsigned div by constants
    // -> magic-multiply, no hardware divide.
    unsigned w4 = idx % W4;
    unsigned t  = idx / W4;
    unsigned h  = t % HH;
    t /= HH;
    unsigned cj = t % (CC * KK);
    unsigned n  = t / (CC * KK);
    unsigned c  = cj / KK;
    unsigned j  = cj % KK;

    int dh = (int)(j / 3u) - 1;
    int dw = (int)(j % 3u) - 1;
    int sh = (int)h + dh;

    float4 v = make_float4(0.f, 0.f, 0.f, 0.f);
    if (sh >= 0 && sh < HH) {
        const float* __restrict__ src = x + ((((size_t)n * CC + c) * HH + (unsigned)sh) * WW);
        int base = (int)(w4 * 4u) + dw;
        float r[4];
#pragma unroll
        for (int e = 0; e < 4; ++e) {
            int sw = base + e;
            r[e] = (sw >= 0 && sw < WW) ? src[sw] : 0.f;
        }
        v = make_float4(r[0], r[1], r[2], r[3]);
    }
    reinterpret_cast<float4*>(out)[idx] = v;  // coalesced 16B store
}

extern "C" void kernel_launch(void* const* d_in, const int* in_sizes, int n_in,
                              void* d_out, int out_size, void* d_ws, size_t ws_size,
                              hipStream_t stream) {
    const float* x = (const float*)d_in[0];
    // d_in[1] is the eye-kernel weight; its effect is baked into the index math.
    float* out = (float*)d_out;

    const unsigned total4 = (unsigned)(NN * CC * KK * HH * W4);  // 28,901,376
    const unsigned blocks = (total4 + 255u) / 256u;
    unfold_kernel<<<blocks, 256, 0, stream>>>(x, out, total4);
}

// Round 3
// 474.730 us; speedup vs baseline: 1.1460x; 1.1460x over previous
//
#include <hip/hip_runtime.h>

// Unfold (im2col) disguised as depthwise conv with eye(9) kernels.
// x: [16, 64, 112, 112] f32 -> out: [16, 64*9, 112, 112] f32
// out[n, c*9 + (kr*3+kc), h, w] = x[n, c, h+kr-1, w+kc-1] (zero pad)
//
// R3 = R2 with native clang vector type (ext_vector_type) so
// __builtin_nontemporal_store accepts it (HIP float4 is a class -> rejected).
// One thread per (n, c, h, w4) produces all 9 kernel-offset outputs from
// 3 input rows held in registers: 3x dwordx4 + 6 edge scalar loads per
// nine 16B nontemporal stores.

#define NN 16
#define CC 64
#define HH 112
#define WW 112
#define W4C 28                 // float4 per row
#define PLANE4 (HH * W4C)      // 3136 float4 per output plane

typedef float v4f __attribute__((ext_vector_type(4)));

__global__ __launch_bounds__(256) void unfold9_kernel(const float* __restrict__ x,
                                                      v4f* __restrict__ out,
                                                      unsigned total) {
    unsigned idx = blockIdx.x * 256u + threadIdx.x;
    if (idx >= total) return;

    unsigned w4 = idx % W4C;
    unsigned t  = idx / W4C;
    unsigned h  = t % HH;
    t /= HH;
    unsigned c  = t % CC;
    unsigned n  = t / CC;

    const float* __restrict__ xc = x + (((size_t)n * CC + c) * HH) * WW;
    unsigned wbase = w4 * 4u;

    v4f   mid[3];
    float lft[3], rgt[3];
#pragma unroll
    for (int kr = 0; kr < 3; ++kr) {
        int sh = (int)h + kr - 1;
        bool ok = (sh >= 0) && (sh < HH);
        const float* __restrict__ row = xc + (unsigned)(ok ? sh : 0) * WW;  // clamped: always safe
        // Unconditional loads from the clamped row, then select to zero —
        // only h=0 / h=111 waves are affected.
        v4f   m = *reinterpret_cast<const v4f*>(row + wbase);
        float l = (w4 > 0u)        ? row[wbase - 1u] : 0.f;
        float r = (w4 < W4C - 1u)  ? row[wbase + 4u] : 0.f;
        if (!ok) { m = (v4f){0.f, 0.f, 0.f, 0.f}; l = 0.f; r = 0.f; }
        mid[kr] = m; lft[kr] = l; rgt[kr] = r;
    }

    // out float4 index for j=0; successive j-planes are PLANE4 apart.
    size_t base = ((size_t)n * (CC * 9) + (size_t)c * 9) * PLANE4
                + (size_t)h * W4C + w4;
#pragma unroll
    for (int kr = 0; kr < 3; ++kr) {
        v4f m = mid[kr];
        v4f a = (v4f){lft[kr], m.x, m.y, m.z};   // kc=0: out[w] = x[w-1]
        v4f b = m;                               // kc=1: identity
        v4f d = (v4f){m.y, m.z, m.w, rgt[kr]};   // kc=2: out[w] = x[w+1]
        __builtin_nontemporal_store(a, &out[base + (size_t)(kr * 3 + 0) * PLANE4]);
        __builtin_nontemporal_store(b, &out[base + (size_t)(kr * 3 + 1) * PLANE4]);
        __builtin_nontemporal_store(d, &out[base + (size_t)(kr * 3 + 2) * PLANE4]);
    }
}

extern "C" void kernel_launch(void* const* d_in, const int* in_sizes, int n_in,
                              void* d_out, int out_size, void* d_ws, size_t ws_size,
                              hipStream_t stream) {
    const float* x = (const float*)d_in[0];
    // d_in[1] (eye-kernel weight) is baked into the index math.
    v4f* out = (v4f*)d_out;

    const unsigned total = (unsigned)(NN * CC * HH * W4C);  // 3,211,264 threads
    const unsigned blocks = (total + 255u) / 256u;          // 12,544 blocks
    unfold9_kernel<<<blocks, 256, 0, stream>>>(x, out, total);
}